// Round 12
// baseline (131.761 us; speedup 1.0000x reference)
//
#include <hip/hip_runtime.h>
#include <cstdint>

// MHA forward, MI355X gfx950.
// cvt(Q,K,V fp32->fp16) ; cvt+transpose(W) ; QKV GEMM (64x128 tile, BK=64,
// 3 blocks/CU, fp16 gld_lds, T3 dbuf; Q pre-scaled; V^T vectorized stores) ;
// flash attention (tri-buffer, 1 barrier/tile, async K+V gld_lds, swapped
// QK^T 32x32x16, in-register softmax, defer-max) ; out GEMM (128x64) -> fp32.
// r12 = r11 + gemm_qkv 64x128 @ 3/CU (was 128x128 @ 2/CU with 33% tail).

typedef _Float16 h4 __attribute__((ext_vector_type(4)));
typedef _Float16 h8 __attribute__((ext_vector_type(8)));
typedef float f4 __attribute__((ext_vector_type(4)));
typedef float f16v __attribute__((ext_vector_type(16)));
typedef unsigned int u32x4 __attribute__((ext_vector_type(4)));
typedef const unsigned int __attribute__((address_space(1)))* gp1_t;
typedef unsigned int __attribute__((address_space(3)))* lp3_t;

// row-dependent granule swizzle: spreads 128B-periodic rows across banks.
#define FSWZ(r) ((((r) ^ ((r) >> 3))) & 7)

__device__ __forceinline__ void gld_lds16(const void* g, const void* l) {
  __builtin_amdgcn_global_load_lds((gp1_t)(uintptr_t)g,
                                   (lp3_t)(unsigned int)(uintptr_t)l, 16, 0, 0);
}
__device__ __forceinline__ unsigned pkh(float a, float b) {
  return __builtin_bit_cast(unsigned, __builtin_amdgcn_cvt_pkrtz(a, b));
}
__device__ __forceinline__ void plswap(unsigned& a, unsigned& b) {
  asm volatile("v_permlane32_swap_b32 %0, %1" : "+v"(a), "+v"(b));
}

// ---------------- converts ----------------

__global__ void cvt_x3(const float* __restrict__ a, const float* __restrict__ b,
                       const float* __restrict__ c, _Float16* __restrict__ out) {
  const int z = blockIdx.z;
  const float* in = (z == 0) ? a : (z == 1) ? b : c;
  _Float16* o = out + (size_t)z * 4194304;
  const int i = (blockIdx.x * 256 + threadIdx.x) * 8;
  float4 u = *(const float4*)(in + i);
  float4 w = *(const float4*)(in + i + 4);
  h8 r = {(_Float16)u.x, (_Float16)u.y, (_Float16)u.z, (_Float16)u.w,
          (_Float16)w.x, (_Float16)w.y, (_Float16)w.z, (_Float16)w.w};
  *(h8*)(o + i) = r;
}

__global__ void cvt_w4(const float* __restrict__ wq, const float* __restrict__ wk,
                       const float* __restrict__ wv, const float* __restrict__ wo,
                       _Float16* __restrict__ WT) {
  const int z = blockIdx.z;
  const float* W = (z == 0) ? wq : (z == 1) ? wk : (z == 2) ? wv : wo;
  _Float16* o = WT + (size_t)z * 1048576;
  const int k = blockIdx.x * 256 + threadIdx.x;
  const int n0 = blockIdx.y * 4;
  float4 w = *(const float4*)(W + (size_t)k * 1024 + n0);
  o[(size_t)(n0 + 0) * 1024 + k] = (_Float16)w.x;
  o[(size_t)(n0 + 1) * 1024 + k] = (_Float16)w.y;
  o[(size_t)(n0 + 2) * 1024 + k] = (_Float16)w.z;
  o[(size_t)(n0 + 3) * 1024 + k] = (_Float16)w.w;
}

// ---------------- QKV GEMM: C[4096x1024] = A16 * Bt^T + bias ----------------
// 64x128 tile, BK=64, 4 waves (2x2, wave tile 32x64). LDS 48KB -> 3 blocks/CU;
// grid (64,8,3) = 1536 = 2 exact rounds of 768 resident (no tail).
// T3 dbuf, pre-swizzled gld_lds + FSWZ reads (rows 128B apart, same math).
// z==0 (Q): scaled by SCALE*log2e. z==2 (V): TRANSPOSED [b][h][hd][s], h4 stores.

#define G_STAGE(BUF, KT)                                                       \
  do {                                                                         \
    _Pragma("unroll") for (int rr_ = 0; rr_ < 2; ++rr_) {                      \
      const int idx_ = rr_ * 256 + tid;                                        \
      const int r_ = idx_ >> 3, g_ = idx_ & 7;                                 \
      gld_lds16(A16 + (size_t)(row0 + r_) * 1024 + (KT) * 64 + (g_ ^ FSWZ(r_)) * 8,\
                &As[BUF][(rr_ * 256 + wave * 64) * 8]);                        \
    }                                                                          \
    _Pragma("unroll") for (int rr_ = 0; rr_ < 4; ++rr_) {                      \
      const int idx_ = rr_ * 256 + tid;                                        \
      const int r_ = idx_ >> 3, g_ = idx_ & 7;                                 \
      gld_lds16(Bt + (size_t)(col0 + r_) * 1024 + (KT) * 64 + (g_ ^ FSWZ(r_)) * 8,\
                &Bs[BUF][(rr_ * 256 + wave * 64) * 8]);                        \
    }                                                                          \
  } while (0)

__global__ __launch_bounds__(256, 3) void gemm_qkv(const _Float16* __restrict__ X16,
                                                   const _Float16* __restrict__ WT,
                                                   const float* __restrict__ bq,
                                                   const float* __restrict__ bk,
                                                   const float* __restrict__ bv,
                                                   _Float16* __restrict__ qkv16) {
  __shared__ _Float16 As[2][4096];  // [64 rows][64 halves]
  __shared__ _Float16 Bs[2][8192];  // [128 rows][64 halves]
  const int z = blockIdx.z;
  const _Float16* A16 = X16 + (size_t)z * 4194304;
  const _Float16* Bt = WT + (size_t)z * 1048576;
  const float* bias = (z == 0) ? bq : (z == 1) ? bk : bv;
  _Float16* out16 = qkv16 + (size_t)z * 4194304;
  const float scl = (z == 0) ? 0.18033688f : 1.0f;  // SCALE*log2e folded into Q
  const int tid = threadIdx.x;
  const int wave = tid >> 6, lane = tid & 63;
  const int lg = lane >> 4, ll = lane & 15;
  const int wr = wave >> 1, wc = wave & 1;
  const int row0 = blockIdx.x * 64, col0 = blockIdx.y * 128;
  f4 acc[2][4] = {};
  G_STAGE(0, 0);
  __syncthreads();
  int cur = 0;
  for (int kt = 0; kt < 16; ++kt) {
    if (kt + 1 < 16) G_STAGE(cur ^ 1, kt + 1);  // loads fly during compute
#pragma unroll
    for (int kk = 0; kk < 2; ++kk) {
      h8 af[2], bf[4];
#pragma unroll
      for (int mi = 0; mi < 2; ++mi) {
        const int r = wr * 32 + mi * 16 + ll;
        af[mi] = *(const h8*)&As[cur][r * 64 + (((kk * 4 + lg) ^ FSWZ(r)) << 3)];
      }
#pragma unroll
      for (int ni = 0; ni < 4; ++ni) {
        const int r = wc * 64 + ni * 16 + ll;
        bf[ni] = *(const h8*)&Bs[cur][r * 64 + (((kk * 4 + lg) ^ FSWZ(r)) << 3)];
      }
#pragma unroll
      for (int mi = 0; mi < 2; ++mi)
#pragma unroll
        for (int ni = 0; ni < 4; ++ni)
          acc[mi][ni] = __builtin_amdgcn_mfma_f32_16x16x32_f16(af[mi], bf[ni],
                                                               acc[mi][ni], 0, 0, 0);
    }
    __syncthreads();
    cur ^= 1;
  }
  if (z == 2) {
    // V^T [B=2][H=16][Hd=64][S=2048]: one 8B h4 store per (mi,ni) along s
#pragma unroll
    for (int ni = 0; ni < 4; ++ni) {
      const int c = col0 + wc * 64 + ni * 16 + ll;  // global hd column
      const float bv = bias[c];
      const int h = c >> 6, hd = c & 63;
#pragma unroll
      for (int mi = 0; mi < 2; ++mi) {
        const int r = row0 + wr * 32 + mi * 16 + lg * 4;  // s-quad base
        const int b = r >> 11, s = r & 2047;
        h4 w = {(_Float16)(acc[mi][ni][0] + bv), (_Float16)(acc[mi][ni][1] + bv),
                (_Float16)(acc[mi][ni][2] + bv), (_Float16)(acc[mi][ni][3] + bv)};
        *(h4*)(out16 + ((size_t)((b * 16 + h) * 64 + hd)) * 2048 + s) = w;
      }
    }
  } else {
#pragma unroll
    for (int ni = 0; ni < 4; ++ni) {
      const int c = col0 + wc * 64 + ni * 16 + ll;
      const float bv = bias[c];
#pragma unroll
      for (int mi = 0; mi < 2; ++mi) {
#pragma unroll
        for (int i = 0; i < 4; ++i) {
          const int r = row0 + wr * 32 + mi * 16 + lg * 4 + i;
          const float val = (acc[mi][ni][i] + bv) * scl;
          const int b = r >> 11, s = r & 2047, h = c >> 6, hd = c & 63;
          out16[((size_t)((b * 16 + h) * 2048 + s)) * 64 + hd] = (_Float16)val;
        }
      }
    }
  }
}

// ---------------- out GEMM: C = A16(4096x1024) * WoT^T + bias -> fp32 ----------------

#define GO_STAGE(BUF, KT)                                                      \
  do {                                                                         \
    _Pragma("unroll") for (int rr_ = 0; rr_ < 4; ++rr_) {                      \
      const int idx_ = rr_ * 256 + tid;                                        \
      const int r_ = idx_ >> 3, g_ = idx_ & 7;                                 \
      gld_lds16(A16 + (size_t)(row0 + r_) * 1024 + (KT) * 64 + (g_ ^ FSWZ(r_)) * 8,\
                &As[BUF][(rr_ * 256 + wave * 64) * 8]);                        \
    }                                                                          \
    _Pragma("unroll") for (int rr_ = 0; rr_ < 2; ++rr_) {                      \
      const int idx_ = rr_ * 256 + tid;                                        \
      const int r_ = idx_ >> 3, g_ = idx_ & 7;                                 \
      gld_lds16(WoT + (size_t)(col0 + r_) * 1024 + (KT) * 64 + (g_ ^ FSWZ(r_)) * 8,\
                &Bs[BUF][(rr_ * 256 + wave * 64) * 8]);                        \
    }                                                                          \
  } while (0)

__global__ __launch_bounds__(256, 3) void gemm_out_k(const _Float16* __restrict__ A16,
                                                     const _Float16* __restrict__ WoT,
                                                     const float* __restrict__ bo,
                                                     float* __restrict__ out) {
  __shared__ _Float16 As[2][8192];
  __shared__ _Float16 Bs[2][4096];
  const int tid = threadIdx.x;
  const int wave = tid >> 6, lane = tid & 63;
  const int lg = lane >> 4, ll = lane & 15;
  const int wr = wave >> 1, wc = wave & 1;
  const int row0 = blockIdx.x * 128, col0 = blockIdx.y * 64;
  f4 acc[4][2] = {};
  GO_STAGE(0, 0);
  __syncthreads();
  int cur = 0;
  for (int kt = 0; kt < 16; ++kt) {
    if (kt + 1 < 16) GO_STAGE(cur ^ 1, kt + 1);
#pragma unroll
    for (int kk = 0; kk < 2; ++kk) {
      h8 af[4], bf[2];
#pragma unroll
      for (int mi = 0; mi < 4; ++mi) {
        const int r = wr * 64 + mi * 16 + ll;
        af[mi] = *(const h8*)&As[cur][r * 64 + (((kk * 4 + lg) ^ FSWZ(r)) << 3)];
      }
#pragma unroll
      for (int ni = 0; ni < 2; ++ni) {
        const int r = wc * 32 + ni * 16 + ll;
        bf[ni] = *(const h8*)&Bs[cur][r * 64 + (((kk * 4 + lg) ^ FSWZ(r)) << 3)];
      }
#pragma unroll
      for (int mi = 0; mi < 4; ++mi)
#pragma unroll
        for (int ni = 0; ni < 2; ++ni)
          acc[mi][ni] = __builtin_amdgcn_mfma_f32_16x16x32_f16(af[mi], bf[ni],
                                                               acc[mi][ni], 0, 0, 0);
    }
    __syncthreads();
    cur ^= 1;
  }
#pragma unroll
  for (int ni = 0; ni < 2; ++ni) {
    const int c = col0 + wc * 32 + ni * 16 + ll;
    const float bv = bo[c];
#pragma unroll
    for (int mi = 0; mi < 4; ++mi)
#pragma unroll
      for (int i = 0; i < 4; ++i) {
        const int r = row0 + wr * 64 + mi * 16 + lg * 4 + i;
        out[(size_t)r * 1024 + c] = acc[mi][ni][i] + bv;
      }
  }
}

// ---------------- flash attention: tri-buffer, one barrier per tile ----------------
// 512 blocks x 256 thr (4 waves x 32 q-rows). Buffers rotate (s0,s1,s2):
// iter t: stage(t+2)->s2 [4 async gld_lds] ; QK(t+1) from s1 ; PV(t) from s0 ;
// softmax+pack(t+1) ; barrier. Both K and V^T staged via gld_lds.

#define STAGE_K(BUF, KT)                                                      \
  do {                                                                        \
    _Pragma("unroll") for (int rr_ = 0; rr_ < 2; ++rr_) {                     \
      const int idx_ = rr_ * 256 + tid;                                       \
      const int r_ = idx_ >> 3, g_ = idx_ & 7;                                \
      gld_lds16(kbp + (size_t)((KT) * 64 + r_) * 64 + ((g_ ^ FSWZ(r_)) * 8),  \
                &Ks[BUF][(rr_ * 256 + wave * 64) * 8]);                       \
    }                                                                         \
  } while (0)

// V^T global [hd][s]: row r_=hd (stride 2048), 8 granules over the 64-key tile
#define STAGE_V(BUF, KT)                                                      \
  do {                                                                        \
    _Pragma("unroll") for (int rr_ = 0; rr_ < 2; ++rr_) {                     \
      const int idx_ = rr_ * 256 + tid;                                       \
      const int r_ = idx_ >> 3, g_ = idx_ & 7;                                \
      gld_lds16(vtp + (size_t)r_ * 2048 + (KT) * 64 + ((g_ ^ FSWZ(r_)) * 8),  \
                &Vt[BUF][(rr_ * 256 + wave * 64) * 8]);                       \
    }                                                                         \
  } while (0)

#define QK_COMPUTE(BUF, S0, S1)                                               \
  do {                                                                        \
    S0 = (f16v){};                                                            \
    S1 = (f16v){};                                                            \
    _Pragma("unroll") for (int kc_ = 0; kc_ < 4; ++kc_) {                     \
      const int c_ = kc_ * 2 + hi;                                            \
      h8 k0_ = *(const h8*)&Ks[BUF][l31 * 64 + ((c_ ^ FSWZ(l31)) << 3)];      \
      h8 k1_ = *(const h8*)&Ks[BUF][(32 + l31) * 64 +                         \
                                    ((c_ ^ FSWZ(32 + l31)) << 3)];            \
      h8 qf_ = (kc_ == 0) ? qf0 : (kc_ == 1) ? qf1 : (kc_ == 2) ? qf2 : qf3;  \
      S0 = __builtin_amdgcn_mfma_f32_32x32x16_f16(k0_, qf_, S0, 0, 0, 0);     \
      S1 = __builtin_amdgcn_mfma_f32_32x32x16_f16(k1_, qf_, S1, 0, 0, 0);     \
    }                                                                         \
  } while (0)

#define PACK_AF(DST, SX, PP)                                                  \
  do {                                                                        \
    unsigned wA = pkh(SX[(PP) + 0], SX[(PP) + 1]);                            \
    unsigned wB = pkh(SX[(PP) + 2], SX[(PP) + 3]);                            \
    unsigned wC = pkh(SX[(PP) + 4], SX[(PP) + 5]);                            \
    unsigned wD = pkh(SX[(PP) + 6], SX[(PP) + 7]);                            \
    plswap(wA, wC);                                                           \
    plswap(wB, wD);                                                           \
    DST = (u32x4){wA, wB, wC, wD};                                            \
  } while (0)

// softmax (log2 domain, Q pre-scaled) -> P packed into afr; update mval/lsum
#define SM_PK(S0, S1)                                                         \
  do {                                                                        \
    float t_[8];                                                              \
    _Pragma("unroll") for (int j2_ = 0; j2_ < 8; ++j2_)                       \
        t_[j2_] = fmaxf(fmaxf(S0[j2_], S0[j2_ + 8]),                          \
                        fmaxf(S1[j2_], S1[j2_ + 8]));                         \
    float pm_ = fmaxf(fmaxf(fmaxf(t_[0], t_[1]), fmaxf(t_[2], t_[3])),        \
                      fmaxf(fmaxf(t_[4], t_[5]), fmaxf(t_[6], t_[7])));       \
    pm_ = fmaxf(pm_, __shfl_xor(pm_, 32));                                    \
    if (__any(pm_ > mval + 8.0f)) {                                           \
      const float mn_ = fmaxf(mval, pm_);                                     \
      const float f_ = __builtin_amdgcn_exp2f(mval - mn_);                    \
      mval = mn_;                                                             \
      lsum *= f_;                                                             \
      Fb[wave][l31] = f_;                                                     \
      const f4 fr0_ = *(const f4*)&Fb[wave][0 + 4 * hi];                      \
      const f4 fr1_ = *(const f4*)&Fb[wave][8 + 4 * hi];                      \
      const f4 fr2_ = *(const f4*)&Fb[wave][16 + 4 * hi];                     \
      const f4 fr3_ = *(const f4*)&Fb[wave][24 + 4 * hi];                     \
      _Pragma("unroll") for (int r_ = 0; r_ < 16; ++r_) {                     \
        const float fx_ =                                                     \
            (r_ < 4 ? fr0_ : r_ < 8 ? fr1_ : r_ < 12 ? fr2_ : fr3_)[r_ & 3];  \
        acc0[r_] *= fx_;                                                      \
        acc1[r_] *= fx_;                                                      \
      }                                                                       \
    }                                                                         \
    _Pragma("unroll") for (int r_ = 0; r_ < 16; ++r_) {                       \
      S0[r_] = __builtin_amdgcn_exp2f(S0[r_] - mval);                         \
      S1[r_] = __builtin_amdgcn_exp2f(S1[r_] - mval);                         \
    }                                                                         \
    float z_[8];                                                              \
    _Pragma("unroll") for (int j2_ = 0; j2_ < 8; ++j2_)                       \
        z_[j2_] = (S0[j2_] + S0[j2_ + 8]) + (S1[j2_] + S1[j2_ + 8]);          \
    lsum += ((z_[0] + z_[1]) + (z_[2] + z_[3])) +                             \
            ((z_[4] + z_[5]) + (z_[6] + z_[7]));                              \
    PACK_AF(afr[0], S0, 0);                                                   \
    PACK_AF(afr[1], S0, 8);                                                   \
    PACK_AF(afr[2], S1, 0);                                                   \
    PACK_AF(afr[3], S1, 8);                                                   \
  } while (0)

#define PV_APPLY(BUF)                                                         \
  do {                                                                        \
    _Pragma("unroll") for (int i_ = 0; i_ < 4; ++i_) {                        \
      const int c_ = i_ * 2 + hi;                                             \
      h8 vf0_ = *(const h8*)&Vt[BUF][l31 * 64 + ((c_ ^ FSWZ(l31)) << 3)];     \
      h8 vf1_ = *(const h8*)&Vt[BUF][(32 + l31) * 64 +                        \
                                     ((c_ ^ FSWZ(32 + l31)) << 3)];           \
      h8 af_ = __builtin_bit_cast(h8, afr[i_]);                               \
      acc0 = __builtin_amdgcn_mfma_f32_32x32x16_f16(af_, vf0_, acc0, 0, 0, 0);\
      acc1 = __builtin_amdgcn_mfma_f32_32x32x16_f16(af_, vf1_, acc1, 0, 0, 0);\
    }                                                                         \
  } while (0)

__global__ __launch_bounds__(256, 2) void attn_kernel(
    const _Float16* __restrict__ q16, const _Float16* __restrict__ k16,
    const _Float16* __restrict__ v16t, _Float16* __restrict__ aout) {
  __shared__ _Float16 Ks[3][4096];  // [64 keys][64 hd] per buf, FSWZ granules
  __shared__ _Float16 Vt[3][4096];  // [64 hd][64 keys] per buf, FSWZ granules
  __shared__ float Fb[4][32];       // per-wave rescale/inv broadcast
  const int tid = threadIdx.x;
  const int wave = tid >> 6, lane = tid & 63;
  const int l31 = lane & 31, hi = lane >> 5;
  // XCD-chunked: xcd = blk&7 owns heads [xcd*4, xcd*4+4)
  const int blk = blockIdx.x;
  const int xcd = blk & 7, j = blk >> 3;   // j in 0..63
  const int bh = xcd * 4 + (j >> 4);
  const int qb = j & 15;
  const int q0w = qb * 128 + wave * 32;
  const _Float16* qbp = q16 + (size_t)bh * 131072;
  const _Float16* kbp = k16 + (size_t)bh * 131072;
  const _Float16* vtp = v16t + (size_t)bh * 131072;  // [hd][s]

  // Q fragments (B-operand), pre-scaled by SCALE*log2e at the GEMM
  h8 qf0 = *(const h8*)(qbp + (size_t)(q0w + l31) * 64 + 0 + hi * 8);
  h8 qf1 = *(const h8*)(qbp + (size_t)(q0w + l31) * 64 + 16 + hi * 8);
  h8 qf2 = *(const h8*)(qbp + (size_t)(q0w + l31) * 64 + 32 + hi * 8);
  h8 qf3 = *(const h8*)(qbp + (size_t)(q0w + l31) * 64 + 48 + hi * 8);

  f16v acc0 = {}, acc1 = {};
  f16v sr0, sr1;
  u32x4 afr[4];
  float mval = -1e30f, lsum = 0.f;

  // ---- prologue: stage tiles 0,1 ; QK(0)+SM(0) ----
  STAGE_K(0, 0);
  STAGE_V(0, 0);
  STAGE_K(1, 1);
  STAGE_V(1, 1);
  __syncthreads();                 // tiles 0,1 resident
  QK_COMPUTE(0, sr0, sr1);
  SM_PK(sr0, sr1);                 // afr = P(0)

  // ---- main loop: one barrier per tile ----
  int s0 = 0, s1 = 1, s2 = 2;      // PV buf / QK buf / stage buf
  for (int t = 0; t < 31; ++t) {
    if (t < 30) { STAGE_K(s2, t + 2); STAGE_V(s2, t + 2); }  // async, lands by barrier
    __builtin_amdgcn_s_setprio(1);
    QK_COMPUTE(s1, sr0, sr1);      // S(t+1)
    PV_APPLY(s0);                  // acc += P(t) * V(t)
    __builtin_amdgcn_s_setprio(0);
    SM_PK(sr0, sr1);               // afr = P(t+1)  (overlaps PV MFMA latency)
    __syncthreads();               // recycles s2's old tile; drains stages
    const int tmp = s0; s0 = s1; s1 = s2; s2 = tmp;
  }
  PV_APPLY(s0);                    // PV(31)

  // ---- epilogue: acc / lsum -> aout [B][S][H*Hd] fp16 ----
  lsum += __shfl_xor(lsum, 32);
  const float inv = 1.0f / lsum;
  Fb[wave][l31] = inv;
  const f4 ir0 = *(const f4*)&Fb[wave][0 + 4 * hi];
  const f4 ir1 = *(const f4*)&Fb[wave][8 + 4 * hi];
  const f4 ir2 = *(const f4*)&Fb[wave][16 + 4 * hi];
  const f4 ir3 = *(const f4*)&Fb[wave][24 + 4 * hi];
  const int b = bh >> 4, h = bh & 15;
#pragma unroll
  for (int r = 0; r < 16; ++r) {
    const float fx = (r < 4 ? ir0 : r < 8 ? ir1 : r < 12 ? ir2 : ir3)[r & 3];
    const int srow = q0w + (r & 3) + 8 * (r >> 2) + 4 * hi;
    _Float16* op = aout + ((size_t)(b * 2048 + srow)) * 1024 + h * 64 + l31;
    op[0] = (_Float16)(acc0[r] * fx);
    op[32] = (_Float16)(acc1[r] * fx);
  }
}

// ---------------- launch ----------------

extern "C" void kernel_launch(void* const* d_in, const int* in_sizes, int n_in,
                              void* d_out, int out_size, void* d_ws, size_t ws_size,
                              hipStream_t stream) {
  const float* Q  = (const float*)d_in[0];
  const float* K  = (const float*)d_in[1];
  const float* V  = (const float*)d_in[2];
  const float* Wq = (const float*)d_in[3];
  const float* bq = (const float*)d_in[4];
  const float* Wk = (const float*)d_in[5];
  const float* bk = (const float*)d_in[6];
  const float* Wv = (const float*)d_in[7];
  const float* bv = (const float*)d_in[8];
  const float* Wo = (const float*)d_in[9];
  const float* bo = (const float*)d_in[10];

  _Float16* H      = (_Float16*)d_ws;
  _Float16* X16    = H;              // 3 x 4194304 (Q,K,V fp16)
  _Float16* WT     = H + 12582912;   // 4 x 1048576 (W^T fp16)
  _Float16* qkv16  = H + 16777216;   // q,k: [B,H,S,Hd]; v: [B,H,Hd,S]
  _Float16* aout16 = H + 29360128;   // 4194304 ([B,S,D] attention out)
  float* out = (float*)d_out;

  cvt_x3<<<dim3(2048, 1, 3), 256, 0, stream>>>(Q, K, V, X16);
  cvt_w4<<<dim3(4, 256, 4), 256, 0, stream>>>(Wq, Wk, Wv, Wo, WT);
  gemm_qkv<<<dim3(64, 8, 3), 256, 0, stream>>>(X16, WT, bq, bk, bv, qkv16);
  attn_kernel<<<dim3(512), 256, 0, stream>>>(qkv16, qkv16 + 4194304,
                                             qkv16 + 8388608, aout16);
  gemm_out_k<<<dim3(32, 16), 256, 0, stream>>>(aout16, WT + 3145728, bo, out);
}

// Round 13
// 126.688 us; speedup vs baseline: 1.0400x; 1.0400x over previous
//
#include <hip/hip_runtime.h>
#include <cstdint>

// MHA forward, MI355X gfx950.
// cvt(Q,K,V fp32->fp16) ; cvt+transpose(W) ; QKV GEMM (128x128, fp16 gld_lds,
// T3 dbuf; Q pre-scaled; V^T vectorized h4 stores) ; flash attention
// (tri-buffer, 1 barrier/tile, async K+V gld_lds, swapped QK^T 32x32x16,
// in-register softmax, defer-max, MFMA ones-column row-sum) ; out GEMM -> fp32.
// r13 = r11 (best, 127.7us) + attn row-sum via ones-MFMA (moves ~25 VALU/tile
// to the 25%-busy MFMA pipe; drops epilogue shfl+broadcast). r12's 64x128
// gemm tile reverted (tile-reuse > occupancy, confirmed twice r7/r12).

typedef _Float16 h4 __attribute__((ext_vector_type(4)));
typedef _Float16 h8 __attribute__((ext_vector_type(8)));
typedef float f4 __attribute__((ext_vector_type(4)));
typedef float f16v __attribute__((ext_vector_type(16)));
typedef unsigned int u32x4 __attribute__((ext_vector_type(4)));
typedef const unsigned int __attribute__((address_space(1)))* gp1_t;
typedef unsigned int __attribute__((address_space(3)))* lp3_t;

// row-dependent granule swizzle: spreads 128B-periodic rows across banks.
#define FSWZ(r) ((((r) ^ ((r) >> 3))) & 7)

__device__ __forceinline__ void gld_lds16(const void* g, const void* l) {
  __builtin_amdgcn_global_load_lds((gp1_t)(uintptr_t)g,
                                   (lp3_t)(unsigned int)(uintptr_t)l, 16, 0, 0);
}
__device__ __forceinline__ unsigned pkh(float a, float b) {
  return __builtin_bit_cast(unsigned, __builtin_amdgcn_cvt_pkrtz(a, b));
}
__device__ __forceinline__ void plswap(unsigned& a, unsigned& b) {
  asm volatile("v_permlane32_swap_b32 %0, %1" : "+v"(a), "+v"(b));
}

// ---------------- converts ----------------

__global__ void cvt_x3(const float* __restrict__ a, const float* __restrict__ b,
                       const float* __restrict__ c, _Float16* __restrict__ out) {
  const int z = blockIdx.z;
  const float* in = (z == 0) ? a : (z == 1) ? b : c;
  _Float16* o = out + (size_t)z * 4194304;
  const int i = (blockIdx.x * 256 + threadIdx.x) * 8;
  float4 u = *(const float4*)(in + i);
  float4 w = *(const float4*)(in + i + 4);
  h8 r = {(_Float16)u.x, (_Float16)u.y, (_Float16)u.z, (_Float16)u.w,
          (_Float16)w.x, (_Float16)w.y, (_Float16)w.z, (_Float16)w.w};
  *(h8*)(o + i) = r;
}

__global__ void cvt_w4(const float* __restrict__ wq, const float* __restrict__ wk,
                       const float* __restrict__ wv, const float* __restrict__ wo,
                       _Float16* __restrict__ WT) {
  const int z = blockIdx.z;
  const float* W = (z == 0) ? wq : (z == 1) ? wk : (z == 2) ? wv : wo;
  _Float16* o = WT + (size_t)z * 1048576;
  const int k = blockIdx.x * 256 + threadIdx.x;
  const int n0 = blockIdx.y * 4;
  float4 w = *(const float4*)(W + (size_t)k * 1024 + n0);
  o[(size_t)(n0 + 0) * 1024 + k] = (_Float16)w.x;
  o[(size_t)(n0 + 1) * 1024 + k] = (_Float16)w.y;
  o[(size_t)(n0 + 2) * 1024 + k] = (_Float16)w.z;
  o[(size_t)(n0 + 3) * 1024 + k] = (_Float16)w.w;
}

// ---------------- QKV GEMM: C[4096x1024] = A16 * Bt^T + bias ----------------
// 128x128 tile, BK=64, T3 dbuf, pre-swizzled gld_lds + FSWZ reads (r11 exact).
// z==0 (Q): scaled by SCALE*log2e. z==2 (V): TRANSPOSED [b][h][hd][s], h4 stores.

#define G_STAGE(BUF, KT)                                                       \
  do {                                                                         \
    _Pragma("unroll") for (int rr_ = 0; rr_ < 4; ++rr_) {                      \
      const int idx_ = rr_ * 256 + tid;                                        \
      const int r_ = idx_ >> 3, g_ = idx_ & 7;                                 \
      const int lb_ = (rr_ * 256 + wave * 64) * 8;                             \
      gld_lds16(A16 + (size_t)(row0 + r_) * 1024 + (KT) * 64 + (g_ ^ FSWZ(r_)) * 8,\
                &As[BUF][lb_]);                                                \
      gld_lds16(Bt + (size_t)(col0 + r_) * 1024 + (KT) * 64 + (g_ ^ FSWZ(r_)) * 8,\
                &Bs[BUF][lb_]);                                                \
    }                                                                          \
  } while (0)

__global__ __launch_bounds__(256, 2) void gemm_qkv(const _Float16* __restrict__ X16,
                                                   const _Float16* __restrict__ WT,
                                                   const float* __restrict__ bq,
                                                   const float* __restrict__ bk,
                                                   const float* __restrict__ bv,
                                                   _Float16* __restrict__ qkv16) {
  __shared__ _Float16 As[2][8192];
  __shared__ _Float16 Bs[2][8192];
  const int z = blockIdx.z;
  const _Float16* A16 = X16 + (size_t)z * 4194304;
  const _Float16* Bt = WT + (size_t)z * 1048576;
  const float* bias = (z == 0) ? bq : (z == 1) ? bk : bv;
  _Float16* out16 = qkv16 + (size_t)z * 4194304;
  const float scl = (z == 0) ? 0.18033688f : 1.0f;  // SCALE*log2e folded into Q
  const int tid = threadIdx.x;
  const int wave = tid >> 6, lane = tid & 63;
  const int lg = lane >> 4, ll = lane & 15;
  const int wr = wave >> 1, wc = wave & 1;
  const int row0 = blockIdx.x * 128, col0 = blockIdx.y * 128;  // x=row: XCD reuse
  f4 acc[4][4] = {};
  G_STAGE(0, 0);
  __syncthreads();
  int cur = 0;
  for (int kt = 0; kt < 16; ++kt) {
    if (kt + 1 < 16) G_STAGE(cur ^ 1, kt + 1);  // loads fly during compute
#pragma unroll
    for (int kk = 0; kk < 2; ++kk) {
      h8 af[4], bf[4];
#pragma unroll
      for (int mi = 0; mi < 4; ++mi) {
        const int r = wr * 64 + mi * 16 + ll;
        af[mi] = *(const h8*)&As[cur][r * 64 + (((kk * 4 + lg) ^ FSWZ(r)) << 3)];
      }
#pragma unroll
      for (int ni = 0; ni < 4; ++ni) {
        const int r = wc * 64 + ni * 16 + ll;
        bf[ni] = *(const h8*)&Bs[cur][r * 64 + (((kk * 4 + lg) ^ FSWZ(r)) << 3)];
      }
#pragma unroll
      for (int mi = 0; mi < 4; ++mi)
#pragma unroll
        for (int ni = 0; ni < 4; ++ni)
          acc[mi][ni] = __builtin_amdgcn_mfma_f32_16x16x32_f16(af[mi], bf[ni],
                                                               acc[mi][ni], 0, 0, 0);
    }
    __syncthreads();
    cur ^= 1;
  }
  if (z == 2) {
    // V^T [B=2][H=16][Hd=64][S=2048]: one 8B h4 store per (mi,ni) along s
#pragma unroll
    for (int ni = 0; ni < 4; ++ni) {
      const int c = col0 + wc * 64 + ni * 16 + ll;  // global hd column
      const float bv = bias[c];
      const int h = c >> 6, hd = c & 63;
#pragma unroll
      for (int mi = 0; mi < 4; ++mi) {
        const int r = row0 + wr * 64 + mi * 16 + lg * 4;  // s-quad base
        const int b = r >> 11, s = r & 2047;
        h4 w = {(_Float16)(acc[mi][ni][0] + bv), (_Float16)(acc[mi][ni][1] + bv),
                (_Float16)(acc[mi][ni][2] + bv), (_Float16)(acc[mi][ni][3] + bv)};
        *(h4*)(out16 + ((size_t)((b * 16 + h) * 64 + hd)) * 2048 + s) = w;
      }
    }
  } else {
#pragma unroll
    for (int ni = 0; ni < 4; ++ni) {
      const int c = col0 + wc * 64 + ni * 16 + ll;
      const float bv = bias[c];
#pragma unroll
      for (int mi = 0; mi < 4; ++mi) {
#pragma unroll
        for (int i = 0; i < 4; ++i) {
          const int r = row0 + wr * 64 + mi * 16 + lg * 4 + i;
          const float val = (acc[mi][ni][i] + bv) * scl;
          const int b = r >> 11, s = r & 2047, h = c >> 6, hd = c & 63;
          out16[((size_t)((b * 16 + h) * 2048 + s)) * 64 + hd] = (_Float16)val;
        }
      }
    }
  }
}

// ---------------- out GEMM: C = A16(4096x1024) * WoT^T + bias -> fp32 ----------------

#define GO_STAGE(BUF, KT)                                                      \
  do {                                                                         \
    _Pragma("unroll") for (int rr_ = 0; rr_ < 4; ++rr_) {                      \
      const int idx_ = rr_ * 256 + tid;                                        \
      const int r_ = idx_ >> 3, g_ = idx_ & 7;                                 \
      gld_lds16(A16 + (size_t)(row0 + r_) * 1024 + (KT) * 64 + (g_ ^ FSWZ(r_)) * 8,\
                &As[BUF][(rr_ * 256 + wave * 64) * 8]);                        \
    }                                                                          \
    _Pragma("unroll") for (int rr_ = 0; rr_ < 2; ++rr_) {                      \
      const int idx_ = rr_ * 256 + tid;                                        \
      const int r_ = idx_ >> 3, g_ = idx_ & 7;                                 \
      gld_lds16(WoT + (size_t)(col0 + r_) * 1024 + (KT) * 64 + (g_ ^ FSWZ(r_)) * 8,\
                &Bs[BUF][(rr_ * 256 + wave * 64) * 8]);                        \
    }                                                                          \
  } while (0)

__global__ __launch_bounds__(256, 3) void gemm_out_k(const _Float16* __restrict__ A16,
                                                     const _Float16* __restrict__ WoT,
                                                     const float* __restrict__ bo,
                                                     float* __restrict__ out) {
  __shared__ _Float16 As[2][8192];
  __shared__ _Float16 Bs[2][4096];
  const int tid = threadIdx.x;
  const int wave = tid >> 6, lane = tid & 63;
  const int lg = lane >> 4, ll = lane & 15;
  const int wr = wave >> 1, wc = wave & 1;
  const int row0 = blockIdx.x * 128, col0 = blockIdx.y * 64;
  f4 acc[4][2] = {};
  GO_STAGE(0, 0);
  __syncthreads();
  int cur = 0;
  for (int kt = 0; kt < 16; ++kt) {
    if (kt + 1 < 16) GO_STAGE(cur ^ 1, kt + 1);
#pragma unroll
    for (int kk = 0; kk < 2; ++kk) {
      h8 af[4], bf[2];
#pragma unroll
      for (int mi = 0; mi < 4; ++mi) {
        const int r = wr * 64 + mi * 16 + ll;
        af[mi] = *(const h8*)&As[cur][r * 64 + (((kk * 4 + lg) ^ FSWZ(r)) << 3)];
      }
#pragma unroll
      for (int ni = 0; ni < 2; ++ni) {
        const int r = wc * 32 + ni * 16 + ll;
        bf[ni] = *(const h8*)&Bs[cur][r * 64 + (((kk * 4 + lg) ^ FSWZ(r)) << 3)];
      }
#pragma unroll
      for (int mi = 0; mi < 4; ++mi)
#pragma unroll
        for (int ni = 0; ni < 2; ++ni)
          acc[mi][ni] = __builtin_amdgcn_mfma_f32_16x16x32_f16(af[mi], bf[ni],
                                                               acc[mi][ni], 0, 0, 0);
    }
    __syncthreads();
    cur ^= 1;
  }
#pragma unroll
  for (int ni = 0; ni < 2; ++ni) {
    const int c = col0 + wc * 32 + ni * 16 + ll;
    const float bv = bo[c];
#pragma unroll
    for (int mi = 0; mi < 4; ++mi)
#pragma unroll
      for (int i = 0; i < 4; ++i) {
        const int r = row0 + wr * 64 + mi * 16 + lg * 4 + i;
        out[(size_t)r * 1024 + c] = acc[mi][ni][i] + bv;
      }
  }
}

// ---------------- flash attention: tri-buffer + ones-MFMA row-sum ----------------
// 512 blocks x 256 thr (4 waves x 32 q-rows). Buffers rotate (s0,s1,s2):
// iter t: stage(t+2)->s2 ; QK(t+1) from s1 ; PV(t) from s0 (incl. accS ones-
// MFMA: denominator on the MFMA pipe) ; softmax+pack(t+1) ; barrier.

#define STAGE_K(BUF, KT)                                                      \
  do {                                                                        \
    _Pragma("unroll") for (int rr_ = 0; rr_ < 2; ++rr_) {                     \
      const int idx_ = rr_ * 256 + tid;                                       \
      const int r_ = idx_ >> 3, g_ = idx_ & 7;                                \
      gld_lds16(kbp + (size_t)((KT) * 64 + r_) * 64 + ((g_ ^ FSWZ(r_)) * 8),  \
                &Ks[BUF][(rr_ * 256 + wave * 64) * 8]);                       \
    }                                                                         \
  } while (0)

// V^T global [hd][s]: row r_=hd (stride 2048), 8 granules over the 64-key tile
#define STAGE_V(BUF, KT)                                                      \
  do {                                                                        \
    _Pragma("unroll") for (int rr_ = 0; rr_ < 2; ++rr_) {                     \
      const int idx_ = rr_ * 256 + tid;                                       \
      const int r_ = idx_ >> 3, g_ = idx_ & 7;                                \
      gld_lds16(vtp + (size_t)r_ * 2048 + (KT) * 64 + ((g_ ^ FSWZ(r_)) * 8),  \
                &Vt[BUF][(rr_ * 256 + wave * 64) * 8]);                       \
    }                                                                         \
  } while (0)

#define QK_COMPUTE(BUF, S0, S1)                                               \
  do {                                                                        \
    S0 = (f16v){};                                                            \
    S1 = (f16v){};                                                            \
    _Pragma("unroll") for (int kc_ = 0; kc_ < 4; ++kc_) {                     \
      const int c_ = kc_ * 2 + hi;                                            \
      h8 k0_ = *(const h8*)&Ks[BUF][l31 * 64 + ((c_ ^ FSWZ(l31)) << 3)];      \
      h8 k1_ = *(const h8*)&Ks[BUF][(32 + l31) * 64 +                         \
                                    ((c_ ^ FSWZ(32 + l31)) << 3)];            \
      h8 qf_ = (kc_ == 0) ? qf0 : (kc_ == 1) ? qf1 : (kc_ == 2) ? qf2 : qf3;  \
      S0 = __builtin_amdgcn_mfma_f32_32x32x16_f16(k0_, qf_, S0, 0, 0, 0);     \
      S1 = __builtin_amdgcn_mfma_f32_32x32x16_f16(k1_, qf_, S1, 0, 0, 0);     \
    }                                                                         \
  } while (0)

#define PACK_AF(DST, SX, PP)                                                  \
  do {                                                                        \
    unsigned wA = pkh(SX[(PP) + 0], SX[(PP) + 1]);                            \
    unsigned wB = pkh(SX[(PP) + 2], SX[(PP) + 3]);                            \
    unsigned wC = pkh(SX[(PP) + 4], SX[(PP) + 5]);                            \
    unsigned wD = pkh(SX[(PP) + 6], SX[(PP) + 7]);                            \
    plswap(wA, wC);                                                           \
    plswap(wB, wD);                                                           \
    DST = (u32x4){wA, wB, wC, wD};                                            \
  } while (0)

// softmax (log2 domain, Q pre-scaled) -> P packed into afr; row-sum deferred
// to the PV ones-MFMA (accS). Only max tracking + exp2 + pack remain on VALU.
#define SM_PK(S0, S1)                                                         \
  do {                                                                        \
    float t_[8];                                                              \
    _Pragma("unroll") for (int j2_ = 0; j2_ < 8; ++j2_)                       \
        t_[j2_] = fmaxf(fmaxf(S0[j2_], S0[j2_ + 8]),                          \
                        fmaxf(S1[j2_], S1[j2_ + 8]));                         \
    float pm_ = fmaxf(fmaxf(fmaxf(t_[0], t_[1]), fmaxf(t_[2], t_[3])),        \
                      fmaxf(fmaxf(t_[4], t_[5]), fmaxf(t_[6], t_[7])));       \
    pm_ = fmaxf(pm_, __shfl_xor(pm_, 32));                                    \
    if (__any(pm_ > mval + 8.0f)) {                                           \
      const float mn_ = fmaxf(mval, pm_);                                     \
      const float f_ = __builtin_amdgcn_exp2f(mval - mn_);                    \
      mval = mn_;                                                             \
      Fb[wave][l31] = f_;                                                     \
      const f4 fr0_ = *(const f4*)&Fb[wave][0 + 4 * hi];                      \
      const f4 fr1_ = *(const f4*)&Fb[wave][8 + 4 * hi];                      \
      const f4 fr2_ = *(const f4*)&Fb[wave][16 + 4 * hi];                     \
      const f4 fr3_ = *(const f4*)&Fb[wave][24 + 4 * hi];                     \
      _Pragma("unroll") for (int r_ = 0; r_ < 16; ++r_) {                     \
        const float fx_ =                                                     \
            (r_ < 4 ? fr0_ : r_ < 8 ? fr1_ : r_ < 12 ? fr2_ : fr3_)[r_ & 3];  \
        acc0[r_] *= fx_;                                                      \
        acc1[r_] *= fx_;                                                      \
        accS[r_] *= fx_;                                                      \
      }                                                                       \
    }                                                                         \
    _Pragma("unroll") for (int r_ = 0; r_ < 16; ++r_) {                       \
      S0[r_] = __builtin_amdgcn_exp2f(S0[r_] - mval);                         \
      S1[r_] = __builtin_amdgcn_exp2f(S1[r_] - mval);                         \
    }                                                                         \
    PACK_AF(afr[0], S0, 0);                                                   \
    PACK_AF(afr[1], S0, 8);                                                   \
    PACK_AF(afr[2], S1, 0);                                                   \
    PACK_AF(afr[3], S1, 8);                                                   \
  } while (0)

#define PV_APPLY(BUF)                                                         \
  do {                                                                        \
    _Pragma("unroll") for (int i_ = 0; i_ < 4; ++i_) {                        \
      const int c_ = i_ * 2 + hi;                                             \
      h8 vf0_ = *(const h8*)&Vt[BUF][l31 * 64 + ((c_ ^ FSWZ(l31)) << 3)];     \
      h8 vf1_ = *(const h8*)&Vt[BUF][(32 + l31) * 64 +                        \
                                     ((c_ ^ FSWZ(32 + l31)) << 3)];           \
      h8 af_ = __builtin_bit_cast(h8, afr[i_]);                               \
      acc0 = __builtin_amdgcn_mfma_f32_32x32x16_f16(af_, vf0_, acc0, 0, 0, 0);\
      acc1 = __builtin_amdgcn_mfma_f32_32x32x16_f16(af_, vf1_, acc1, 0, 0, 0);\
      accS = __builtin_amdgcn_mfma_f32_32x32x16_f16(af_, vone, accS, 0, 0, 0);\
    }                                                                         \
  } while (0)

__global__ __launch_bounds__(256, 2) void attn_kernel(
    const _Float16* __restrict__ q16, const _Float16* __restrict__ k16,
    const _Float16* __restrict__ v16t, _Float16* __restrict__ aout) {
  __shared__ _Float16 Ks[3][4096];  // [64 keys][64 hd] per buf, FSWZ granules
  __shared__ _Float16 Vt[3][4096];  // [64 hd][64 keys] per buf, FSWZ granules
  __shared__ float Fb[4][32];       // per-wave rescale broadcast
  const int tid = threadIdx.x;
  const int wave = tid >> 6, lane = tid & 63;
  const int l31 = lane & 31, hi = lane >> 5;
  // XCD-chunked: xcd = blk&7 owns heads [xcd*4, xcd*4+4)
  const int blk = blockIdx.x;
  const int xcd = blk & 7, j = blk >> 3;   // j in 0..63
  const int bh = xcd * 4 + (j >> 4);
  const int qb = j & 15;
  const int q0w = qb * 128 + wave * 32;
  const _Float16* qbp = q16 + (size_t)bh * 131072;
  const _Float16* kbp = k16 + (size_t)bh * 131072;
  const _Float16* vtp = v16t + (size_t)bh * 131072;  // [hd][s]

  // Q fragments (B-operand), pre-scaled by SCALE*log2e at the GEMM
  h8 qf0 = *(const h8*)(qbp + (size_t)(q0w + l31) * 64 + 0 + hi * 8);
  h8 qf1 = *(const h8*)(qbp + (size_t)(q0w + l31) * 64 + 16 + hi * 8);
  h8 qf2 = *(const h8*)(qbp + (size_t)(q0w + l31) * 64 + 32 + hi * 8);
  h8 qf3 = *(const h8*)(qbp + (size_t)(q0w + l31) * 64 + 48 + hi * 8);

  const h8 vone = {(_Float16)1.f, (_Float16)1.f, (_Float16)1.f, (_Float16)1.f,
                   (_Float16)1.f, (_Float16)1.f, (_Float16)1.f, (_Float16)1.f};
  f16v acc0 = {}, acc1 = {}, accS = {};
  f16v sr0, sr1;
  u32x4 afr[4];
  float mval = -1e30f;

  // ---- prologue: stage tiles 0,1 ; QK(0)+SM(0) ----
  STAGE_K(0, 0);
  STAGE_V(0, 0);
  STAGE_K(1, 1);
  STAGE_V(1, 1);
  __syncthreads();                 // tiles 0,1 resident
  QK_COMPUTE(0, sr0, sr1);
  SM_PK(sr0, sr1);                 // afr = P(0)

  // ---- main loop: one barrier per tile ----
  int s0 = 0, s1 = 1, s2 = 2;      // PV buf / QK buf / stage buf
  for (int t = 0; t < 31; ++t) {
    if (t < 30) { STAGE_K(s2, t + 2); STAGE_V(s2, t + 2); }  // async, lands by barrier
    __builtin_amdgcn_s_setprio(1);
    QK_COMPUTE(s1, sr0, sr1);      // S(t+1)
    PV_APPLY(s0);                  // acc += P(t) * V(t); accS += rowsum(P(t))
    __builtin_amdgcn_s_setprio(0);
    SM_PK(sr0, sr1);               // afr = P(t+1)  (overlaps PV MFMA latency)
    __syncthreads();               // recycles s2's old tile; drains stages
    const int tmp = s0; s0 = s1; s1 = s2; s2 = tmp;
  }
  PV_APPLY(s0);                    // PV(31)

  // ---- epilogue: acc / accS -> aout [B][S][H*Hd] fp16 ----
  // accS[r] = full row-sum for q-row srow(r) (uniform across lanes; the
  // ones-MFMA reduces over all 64 lanes' key slots). No shfl/broadcast needed.
  const int b = bh >> 4, h = bh & 15;
#pragma unroll
  for (int r = 0; r < 16; ++r) {
    const float fx = 1.0f / accS[r];
    const int srow = q0w + (r & 3) + 8 * (r >> 2) + 4 * hi;
    _Float16* op = aout + ((size_t)(b * 2048 + srow)) * 1024 + h * 64 + l31;
    op[0] = (_Float16)(acc0[r] * fx);
    op[32] = (_Float16)(acc1[r] * fx);
  }
}

// ---------------- launch ----------------

extern "C" void kernel_launch(void* const* d_in, const int* in_sizes, int n_in,
                              void* d_out, int out_size, void* d_ws, size_t ws_size,
                              hipStream_t stream) {
  const float* Q  = (const float*)d_in[0];
  const float* K  = (const float*)d_in[1];
  const float* V  = (const float*)d_in[2];
  const float* Wq = (const float*)d_in[3];
  const float* bq = (const float*)d_in[4];
  const float* Wk = (const float*)d_in[5];
  const float* bk = (const float*)d_in[6];
  const float* Wv = (const float*)d_in[7];
  const float* bv = (const float*)d_in[8];
  const float* Wo = (const float*)d_in[9];
  const float* bo = (const float*)d_in[10];

  _Float16* H      = (_Float16*)d_ws;
  _Float16* X16    = H;              // 3 x 4194304 (Q,K,V fp16)
  _Float16* WT     = H + 12582912;   // 4 x 1048576 (W^T fp16)
  _Float16* qkv16  = H + 16777216;   // q,k: [B,H,S,Hd]; v: [B,H,Hd,S]
  _Float16* aout16 = H + 29360128;   // 4194304 ([B,S,D] attention out)
  float* out = (float*)d_out;

  cvt_x3<<<dim3(2048, 1, 3), 256, 0, stream>>>(Q, K, V, X16);
  cvt_w4<<<dim3(4, 256, 4), 256, 0, stream>>>(Wq, Wk, Wv, Wo, WT);
  gemm_qkv<<<dim3(32, 8, 3), 256, 0, stream>>>(X16, WT, bq, bk, bv, qkv16);
  attn_kernel<<<dim3(512), 256, 0, stream>>>(qkv16, qkv16 + 4194304,
                                             qkv16 + 8388608, aout16);
  gemm_out_k<<<dim3(32, 16), 256, 0, stream>>>(aout16, WT + 3145728, bo, out);
}

// Round 14
// 125.956 us; speedup vs baseline: 1.0461x; 1.0058x over previous
//
#include <hip/hip_runtime.h>
#include <cstdint>

// MHA forward, MI355X gfx950.
// cvt(Q,K,V fp32->fp16) ; cvt+transpose(W) ; QKV GEMM (128x128, fp16 gld_lds,
// T3 dbuf; Q pre-scaled; V^T h4 stores) ; flash attention (tri-buffer UNROLLED
// x3 -> compile-time LDS offsets; 1 barrier/tile; async K+V gld_lds; swapped
// QK^T 32x32x16; in-register softmax; defer-max; ones-MFMA row-sum) ;
// out GEMM (128x128, 256 blocks = 1/CU) -> fp32.
// r14 = r13 + {attn x3 unroll (kills runtime-rotation addressing VALU),
// gemm_out 128x128 (B-reuse 2x)}.

typedef _Float16 h4 __attribute__((ext_vector_type(4)));
typedef _Float16 h8 __attribute__((ext_vector_type(8)));
typedef float f4 __attribute__((ext_vector_type(4)));
typedef float f16v __attribute__((ext_vector_type(16)));
typedef unsigned int u32x4 __attribute__((ext_vector_type(4)));
typedef const unsigned int __attribute__((address_space(1)))* gp1_t;
typedef unsigned int __attribute__((address_space(3)))* lp3_t;

// row-dependent granule swizzle: spreads 128B-periodic rows across banks.
#define FSWZ(r) ((((r) ^ ((r) >> 3))) & 7)

__device__ __forceinline__ void gld_lds16(const void* g, const void* l) {
  __builtin_amdgcn_global_load_lds((gp1_t)(uintptr_t)g,
                                   (lp3_t)(unsigned int)(uintptr_t)l, 16, 0, 0);
}
__device__ __forceinline__ unsigned pkh(float a, float b) {
  return __builtin_bit_cast(unsigned, __builtin_amdgcn_cvt_pkrtz(a, b));
}
__device__ __forceinline__ void plswap(unsigned& a, unsigned& b) {
  asm volatile("v_permlane32_swap_b32 %0, %1" : "+v"(a), "+v"(b));
}

// ---------------- converts ----------------

__global__ void cvt_x3(const float* __restrict__ a, const float* __restrict__ b,
                       const float* __restrict__ c, _Float16* __restrict__ out) {
  const int z = blockIdx.z;
  const float* in = (z == 0) ? a : (z == 1) ? b : c;
  _Float16* o = out + (size_t)z * 4194304;
  const int i = (blockIdx.x * 256 + threadIdx.x) * 8;
  float4 u = *(const float4*)(in + i);
  float4 w = *(const float4*)(in + i + 4);
  h8 r = {(_Float16)u.x, (_Float16)u.y, (_Float16)u.z, (_Float16)u.w,
          (_Float16)w.x, (_Float16)w.y, (_Float16)w.z, (_Float16)w.w};
  *(h8*)(o + i) = r;
}

__global__ void cvt_w4(const float* __restrict__ wq, const float* __restrict__ wk,
                       const float* __restrict__ wv, const float* __restrict__ wo,
                       _Float16* __restrict__ WT) {
  const int z = blockIdx.z;
  const float* W = (z == 0) ? wq : (z == 1) ? wk : (z == 2) ? wv : wo;
  _Float16* o = WT + (size_t)z * 1048576;
  const int k = blockIdx.x * 256 + threadIdx.x;
  const int n0 = blockIdx.y * 4;
  float4 w = *(const float4*)(W + (size_t)k * 1024 + n0);
  o[(size_t)(n0 + 0) * 1024 + k] = (_Float16)w.x;
  o[(size_t)(n0 + 1) * 1024 + k] = (_Float16)w.y;
  o[(size_t)(n0 + 2) * 1024 + k] = (_Float16)w.z;
  o[(size_t)(n0 + 3) * 1024 + k] = (_Float16)w.w;
}

// ---------------- QKV GEMM: C[4096x1024] = A16 * Bt^T + bias ----------------
// 128x128 tile, BK=64, T3 dbuf, pre-swizzled gld_lds + FSWZ reads (r11 exact).
// z==0 (Q): scaled by SCALE*log2e. z==2 (V): TRANSPOSED [b][h][hd][s], h4 stores.

#define G_STAGE(BUF, KT)                                                       \
  do {                                                                         \
    _Pragma("unroll") for (int rr_ = 0; rr_ < 4; ++rr_) {                      \
      const int idx_ = rr_ * 256 + tid;                                        \
      const int r_ = idx_ >> 3, g_ = idx_ & 7;                                 \
      const int lb_ = (rr_ * 256 + wave * 64) * 8;                             \
      gld_lds16(A16 + (size_t)(row0 + r_) * 1024 + (KT) * 64 + (g_ ^ FSWZ(r_)) * 8,\
                &As[BUF][lb_]);                                                \
      gld_lds16(Bt + (size_t)(col0 + r_) * 1024 + (KT) * 64 + (g_ ^ FSWZ(r_)) * 8,\
                &Bs[BUF][lb_]);                                                \
    }                                                                          \
  } while (0)

__global__ __launch_bounds__(256, 2) void gemm_qkv(const _Float16* __restrict__ X16,
                                                   const _Float16* __restrict__ WT,
                                                   const float* __restrict__ bq,
                                                   const float* __restrict__ bk,
                                                   const float* __restrict__ bv,
                                                   _Float16* __restrict__ qkv16) {
  __shared__ _Float16 As[2][8192];
  __shared__ _Float16 Bs[2][8192];
  const int z = blockIdx.z;
  const _Float16* A16 = X16 + (size_t)z * 4194304;
  const _Float16* Bt = WT + (size_t)z * 1048576;
  const float* bias = (z == 0) ? bq : (z == 1) ? bk : bv;
  _Float16* out16 = qkv16 + (size_t)z * 4194304;
  const float scl = (z == 0) ? 0.18033688f : 1.0f;  // SCALE*log2e folded into Q
  const int tid = threadIdx.x;
  const int wave = tid >> 6, lane = tid & 63;
  const int lg = lane >> 4, ll = lane & 15;
  const int wr = wave >> 1, wc = wave & 1;
  const int row0 = blockIdx.x * 128, col0 = blockIdx.y * 128;  // x=row: XCD reuse
  f4 acc[4][4] = {};
  G_STAGE(0, 0);
  __syncthreads();
  int cur = 0;
  for (int kt = 0; kt < 16; ++kt) {
    if (kt + 1 < 16) G_STAGE(cur ^ 1, kt + 1);  // loads fly during compute
#pragma unroll
    for (int kk = 0; kk < 2; ++kk) {
      h8 af[4], bf[4];
#pragma unroll
      for (int mi = 0; mi < 4; ++mi) {
        const int r = wr * 64 + mi * 16 + ll;
        af[mi] = *(const h8*)&As[cur][r * 64 + (((kk * 4 + lg) ^ FSWZ(r)) << 3)];
      }
#pragma unroll
      for (int ni = 0; ni < 4; ++ni) {
        const int r = wc * 64 + ni * 16 + ll;
        bf[ni] = *(const h8*)&Bs[cur][r * 64 + (((kk * 4 + lg) ^ FSWZ(r)) << 3)];
      }
#pragma unroll
      for (int mi = 0; mi < 4; ++mi)
#pragma unroll
        for (int ni = 0; ni < 4; ++ni)
          acc[mi][ni] = __builtin_amdgcn_mfma_f32_16x16x32_f16(af[mi], bf[ni],
                                                               acc[mi][ni], 0, 0, 0);
    }
    __syncthreads();
    cur ^= 1;
  }
  if (z == 2) {
    // V^T [B=2][H=16][Hd=64][S=2048]: one 8B h4 store per (mi,ni) along s
#pragma unroll
    for (int ni = 0; ni < 4; ++ni) {
      const int c = col0 + wc * 64 + ni * 16 + ll;  // global hd column
      const float bv = bias[c];
      const int h = c >> 6, hd = c & 63;
#pragma unroll
      for (int mi = 0; mi < 4; ++mi) {
        const int r = row0 + wr * 64 + mi * 16 + lg * 4;  // s-quad base
        const int b = r >> 11, s = r & 2047;
        h4 w = {(_Float16)(acc[mi][ni][0] + bv), (_Float16)(acc[mi][ni][1] + bv),
                (_Float16)(acc[mi][ni][2] + bv), (_Float16)(acc[mi][ni][3] + bv)};
        *(h4*)(out16 + ((size_t)((b * 16 + h) * 64 + hd)) * 2048 + s) = w;
      }
    }
  } else {
#pragma unroll
    for (int ni = 0; ni < 4; ++ni) {
      const int c = col0 + wc * 64 + ni * 16 + ll;
      const float bv = bias[c];
#pragma unroll
      for (int mi = 0; mi < 4; ++mi) {
#pragma unroll
        for (int i = 0; i < 4; ++i) {
          const int r = row0 + wr * 64 + mi * 16 + lg * 4 + i;
          const float val = (acc[mi][ni][i] + bv) * scl;
          const int b = r >> 11, s = r & 2047, h = c >> 6, hd = c & 63;
          out16[((size_t)((b * 16 + h) * 2048 + s)) * 64 + hd] = (_Float16)val;
        }
      }
    }
  }
}

// ---------------- out GEMM: C[4096x1024] = A16 * WoT^T + bias -> fp32 ----------------
// 128x128 tile (B-reuse 2x vs 128x64); grid (32,8) = 256 blocks = 1/CU exact.

#define GO_STAGE(BUF, KT)                                                      \
  do {                                                                         \
    _Pragma("unroll") for (int rr_ = 0; rr_ < 4; ++rr_) {                      \
      const int idx_ = rr_ * 256 + tid;                                        \
      const int r_ = idx_ >> 3, g_ = idx_ & 7;                                 \
      const int lb_ = (rr_ * 256 + wave * 64) * 8;                             \
      gld_lds16(A16 + (size_t)(row0 + r_) * 1024 + (KT) * 64 + (g_ ^ FSWZ(r_)) * 8,\
                &As[BUF][lb_]);                                                \
      gld_lds16(WoT + (size_t)(col0 + r_) * 1024 + (KT) * 64 + (g_ ^ FSWZ(r_)) * 8,\
                &Bs[BUF][lb_]);                                                \
    }                                                                          \
  } while (0)

__global__ __launch_bounds__(256, 2) void gemm_out_k(const _Float16* __restrict__ A16,
                                                     const _Float16* __restrict__ WoT,
                                                     const float* __restrict__ bo,
                                                     float* __restrict__ out) {
  __shared__ _Float16 As[2][8192];
  __shared__ _Float16 Bs[2][8192];
  const int tid = threadIdx.x;
  const int wave = tid >> 6, lane = tid & 63;
  const int lg = lane >> 4, ll = lane & 15;
  const int wr = wave >> 1, wc = wave & 1;
  const int row0 = blockIdx.x * 128, col0 = blockIdx.y * 128;
  f4 acc[4][4] = {};
  GO_STAGE(0, 0);
  __syncthreads();
  int cur = 0;
  for (int kt = 0; kt < 16; ++kt) {
    if (kt + 1 < 16) GO_STAGE(cur ^ 1, kt + 1);
#pragma unroll
    for (int kk = 0; kk < 2; ++kk) {
      h8 af[4], bf[4];
#pragma unroll
      for (int mi = 0; mi < 4; ++mi) {
        const int r = wr * 64 + mi * 16 + ll;
        af[mi] = *(const h8*)&As[cur][r * 64 + (((kk * 4 + lg) ^ FSWZ(r)) << 3)];
      }
#pragma unroll
      for (int ni = 0; ni < 4; ++ni) {
        const int r = wc * 64 + ni * 16 + ll;
        bf[ni] = *(const h8*)&Bs[cur][r * 64 + (((kk * 4 + lg) ^ FSWZ(r)) << 3)];
      }
#pragma unroll
      for (int mi = 0; mi < 4; ++mi)
#pragma unroll
        for (int ni = 0; ni < 4; ++ni)
          acc[mi][ni] = __builtin_amdgcn_mfma_f32_16x16x32_f16(af[mi], bf[ni],
                                                               acc[mi][ni], 0, 0, 0);
    }
    __syncthreads();
    cur ^= 1;
  }
#pragma unroll
  for (int ni = 0; ni < 4; ++ni) {
    const int c = col0 + wc * 64 + ni * 16 + ll;
    const float bv = bo[c];
#pragma unroll
    for (int mi = 0; mi < 4; ++mi)
#pragma unroll
      for (int i = 0; i < 4; ++i) {
        const int r = row0 + wr * 64 + mi * 16 + lg * 4 + i;
        out[(size_t)r * 1024 + c] = acc[mi][ni][i] + bv;
      }
  }
}

// ---------------- flash attention: tri-buffer, unrolled x3 ----------------
// 512 blocks x 256 thr (4 waves x 32 q-rows). Buffer roles are COMPILE-TIME
// via x3 unroll (tile t lives in buffer t%3): LDS bases fold to immediates.
// iter t: stage(t+2)->buf[(t+2)%3] ; QK(t+1) ; PV(t)+accS ; SM_PK(t+1) ; bar.

#define STAGE_K(BUF, KT)                                                      \
  do {                                                                        \
    _Pragma("unroll") for (int rr_ = 0; rr_ < 2; ++rr_) {                     \
      const int idx_ = rr_ * 256 + tid;                                       \
      const int r_ = idx_ >> 3, g_ = idx_ & 7;                                \
      gld_lds16(kbp + (size_t)((KT) * 64 + r_) * 64 + ((g_ ^ FSWZ(r_)) * 8),  \
                &Ks[BUF][(rr_ * 256 + wave * 64) * 8]);                       \
    }                                                                         \
  } while (0)

#define STAGE_V(BUF, KT)                                                      \
  do {                                                                        \
    _Pragma("unroll") for (int rr_ = 0; rr_ < 2; ++rr_) {                     \
      const int idx_ = rr_ * 256 + tid;                                       \
      const int r_ = idx_ >> 3, g_ = idx_ & 7;                                \
      gld_lds16(vtp + (size_t)r_ * 2048 + (KT) * 64 + ((g_ ^ FSWZ(r_)) * 8),  \
                &Vt[BUF][(rr_ * 256 + wave * 64) * 8]);                       \
    }                                                                         \
  } while (0)

#define QK_COMPUTE(BUF, S0, S1)                                               \
  do {                                                                        \
    S0 = (f16v){};                                                            \
    S1 = (f16v){};                                                            \
    _Pragma("unroll") for (int kc_ = 0; kc_ < 4; ++kc_) {                     \
      const int c_ = kc_ * 2 + hi;                                            \
      h8 k0_ = *(const h8*)&Ks[BUF][l31 * 64 + ((c_ ^ FSWZ(l31)) << 3)];      \
      h8 k1_ = *(const h8*)&Ks[BUF][(32 + l31) * 64 +                         \
                                    ((c_ ^ FSWZ(32 + l31)) << 3)];            \
      h8 qf_ = (kc_ == 0) ? qf0 : (kc_ == 1) ? qf1 : (kc_ == 2) ? qf2 : qf3;  \
      S0 = __builtin_amdgcn_mfma_f32_32x32x16_f16(k0_, qf_, S0, 0, 0, 0);     \
      S1 = __builtin_amdgcn_mfma_f32_32x32x16_f16(k1_, qf_, S1, 0, 0, 0);     \
    }                                                                         \
  } while (0)

#define PACK_AF(DST, SX, PP)                                                  \
  do {                                                                        \
    unsigned wA = pkh(SX[(PP) + 0], SX[(PP) + 1]);                            \
    unsigned wB = pkh(SX[(PP) + 2], SX[(PP) + 3]);                            \
    unsigned wC = pkh(SX[(PP) + 4], SX[(PP) + 5]);                            \
    unsigned wD = pkh(SX[(PP) + 6], SX[(PP) + 7]);                            \
    plswap(wA, wC);                                                           \
    plswap(wB, wD);                                                           \
    DST = (u32x4){wA, wB, wC, wD};                                            \
  } while (0)

// softmax (log2 domain, Q pre-scaled) -> P packed into afr; row-sum on MFMA
#define SM_PK(S0, S1)                                                         \
  do {                                                                        \
    float t_[8];                                                              \
    _Pragma("unroll") for (int j2_ = 0; j2_ < 8; ++j2_)                       \
        t_[j2_] = fmaxf(fmaxf(S0[j2_], S0[j2_ + 8]),                          \
                        fmaxf(S1[j2_], S1[j2_ + 8]));                         \
    float pm_ = fmaxf(fmaxf(fmaxf(t_[0], t_[1]), fmaxf(t_[2], t_[3])),        \
                      fmaxf(fmaxf(t_[4], t_[5]), fmaxf(t_[6], t_[7])));       \
    pm_ = fmaxf(pm_, __shfl_xor(pm_, 32));                                    \
    if (__any(pm_ > mval + 8.0f)) {                                           \
      const float mn_ = fmaxf(mval, pm_);                                     \
      const float f_ = __builtin_amdgcn_exp2f(mval - mn_);                    \
      mval = mn_;                                                             \
      Fb[wave][l31] = f_;                                                     \
      const f4 fr0_ = *(const f4*)&Fb[wave][0 + 4 * hi];                      \
      const f4 fr1_ = *(const f4*)&Fb[wave][8 + 4 * hi];                      \
      const f4 fr2_ = *(const f4*)&Fb[wave][16 + 4 * hi];                     \
      const f4 fr3_ = *(const f4*)&Fb[wave][24 + 4 * hi];                     \
      _Pragma("unroll") for (int r_ = 0; r_ < 16; ++r_) {                     \
        const float fx_ =                                                     \
            (r_ < 4 ? fr0_ : r_ < 8 ? fr1_ : r_ < 12 ? fr2_ : fr3_)[r_ & 3];  \
        acc0[r_] *= fx_;                                                      \
        acc1[r_] *= fx_;                                                      \
        accS[r_] *= fx_;                                                      \
      }                                                                       \
    }                                                                         \
    _Pragma("unroll") for (int r_ = 0; r_ < 16; ++r_) {                       \
      S0[r_] = __builtin_amdgcn_exp2f(S0[r_] - mval);                         \
      S1[r_] = __builtin_amdgcn_exp2f(S1[r_] - mval);                         \
    }                                                                         \
    PACK_AF(afr[0], S0, 0);                                                   \
    PACK_AF(afr[1], S0, 8);                                                   \
    PACK_AF(afr[2], S1, 0);                                                   \
    PACK_AF(afr[3], S1, 8);                                                   \
  } while (0)

#define PV_APPLY(BUF)                                                         \
  do {                                                                        \
    _Pragma("unroll") for (int i_ = 0; i_ < 4; ++i_) {                        \
      const int c_ = i_ * 2 + hi;                                             \
      h8 vf0_ = *(const h8*)&Vt[BUF][l31 * 64 + ((c_ ^ FSWZ(l31)) << 3)];     \
      h8 vf1_ = *(const h8*)&Vt[BUF][(32 + l31) * 64 +                        \
                                     ((c_ ^ FSWZ(32 + l31)) << 3)];           \
      h8 af_ = __builtin_bit_cast(h8, afr[i_]);                               \
      acc0 = __builtin_amdgcn_mfma_f32_32x32x16_f16(af_, vf0_, acc0, 0, 0, 0);\
      acc1 = __builtin_amdgcn_mfma_f32_32x32x16_f16(af_, vf1_, acc1, 0, 0, 0);\
      accS = __builtin_amdgcn_mfma_f32_32x32x16_f16(af_, vone, accS, 0, 0, 0);\
    }                                                                         \
  } while (0)

// one unrolled iteration: A=t%3 (PV buf), B=(t+1)%3 (QK buf), C=(t+2)%3 (stage)
#define ATTN_ITER(T, A, B, C)                                                 \
  do {                                                                        \
    STAGE_K(C, (T) + 2);                                                      \
    STAGE_V(C, (T) + 2);                                                      \
    __builtin_amdgcn_s_setprio(1);                                            \
    QK_COMPUTE(B, sr0, sr1);                                                  \
    PV_APPLY(A);                                                              \
    __builtin_amdgcn_s_setprio(0);                                            \
    SM_PK(sr0, sr1);                                                          \
    __syncthreads();                                                          \
  } while (0)

__global__ __launch_bounds__(256, 2) void attn_kernel(
    const _Float16* __restrict__ q16, const _Float16* __restrict__ k16,
    const _Float16* __restrict__ v16t, _Float16* __restrict__ aout) {
  __shared__ _Float16 Ks[3][4096];  // [64 keys][64 hd] per buf, FSWZ granules
  __shared__ _Float16 Vt[3][4096];  // [64 hd][64 keys] per buf, FSWZ granules
  __shared__ float Fb[4][32];       // per-wave rescale broadcast
  const int tid = threadIdx.x;
  const int wave = tid >> 6, lane = tid & 63;
  const int l31 = lane & 31, hi = lane >> 5;
  // XCD-chunked: xcd = blk&7 owns heads [xcd*4, xcd*4+4)
  const int blk = blockIdx.x;
  const int xcd = blk & 7, j = blk >> 3;   // j in 0..63
  const int bh = xcd * 4 + (j >> 4);
  const int qb = j & 15;
  const int q0w = qb * 128 + wave * 32;
  const _Float16* qbp = q16 + (size_t)bh * 131072;
  const _Float16* kbp = k16 + (size_t)bh * 131072;
  const _Float16* vtp = v16t + (size_t)bh * 131072;  // [hd][s]

  // Q fragments (B-operand), pre-scaled by SCALE*log2e at the GEMM
  h8 qf0 = *(const h8*)(qbp + (size_t)(q0w + l31) * 64 + 0 + hi * 8);
  h8 qf1 = *(const h8*)(qbp + (size_t)(q0w + l31) * 64 + 16 + hi * 8);
  h8 qf2 = *(const h8*)(qbp + (size_t)(q0w + l31) * 64 + 32 + hi * 8);
  h8 qf3 = *(const h8*)(qbp + (size_t)(q0w + l31) * 64 + 48 + hi * 8);

  const h8 vone = {(_Float16)1.f, (_Float16)1.f, (_Float16)1.f, (_Float16)1.f,
                   (_Float16)1.f, (_Float16)1.f, (_Float16)1.f, (_Float16)1.f};
  f16v acc0 = {}, acc1 = {}, accS = {};
  f16v sr0, sr1;
  u32x4 afr[4];
  float mval = -1e30f;

  // ---- prologue: stage tiles 0,1 ; QK(0)+SM(0) ----
  STAGE_K(0, 0);
  STAGE_V(0, 0);
  STAGE_K(1, 1);
  STAGE_V(1, 1);
  __syncthreads();                 // tiles 0,1 resident
  QK_COMPUTE(0, sr0, sr1);
  SM_PK(sr0, sr1);                 // afr = P(0)

  // ---- main loop, unrolled x3 (t = 0..29), buffer roles compile-time ----
  for (int tb = 0; tb < 30; tb += 3) {
    ATTN_ITER(tb + 0, 0, 1, 2);
    ATTN_ITER(tb + 1, 1, 2, 0);
    ATTN_ITER(tb + 2, 2, 0, 1);
  }
  // ---- t = 30 (no staging): QK(31) from buf 1 ; PV(30) from buf 0 ----
  __builtin_amdgcn_s_setprio(1);
  QK_COMPUTE(1, sr0, sr1);
  PV_APPLY(0);
  __builtin_amdgcn_s_setprio(0);
  SM_PK(sr0, sr1);
  PV_APPLY(1);                     // PV(31): tile 31 lives in buffer 1

  // ---- epilogue: acc / accS -> aout [B][S][H*Hd] fp16 ----
  const int b = bh >> 4, h = bh & 15;
#pragma unroll
  for (int r = 0; r < 16; ++r) {
    const float fx = 1.0f / accS[r];
    const int srow = q0w + (r & 3) + 8 * (r >> 2) + 4 * hi;
    _Float16* op = aout + ((size_t)(b * 2048 + srow)) * 1024 + h * 64 + l31;
    op[0] = (_Float16)(acc0[r] * fx);
    op[32] = (_Float16)(acc1[r] * fx);
  }
}

// ---------------- launch ----------------

extern "C" void kernel_launch(void* const* d_in, const int* in_sizes, int n_in,
                              void* d_out, int out_size, void* d_ws, size_t ws_size,
                              hipStream_t stream) {
  const float* Q  = (const float*)d_in[0];
  const float* K  = (const float*)d_in[1];
  const float* V  = (const float*)d_in[2];
  const float* Wq = (const float*)d_in[3];
  const float* bq = (const float*)d_in[4];
  const float* Wk = (const float*)d_in[5];
  const float* bk = (const float*)d_in[6];
  const float* Wv = (const float*)d_in[7];
  const float* bv = (const float*)d_in[8];
  const float* Wo = (const float*)d_in[9];
  const float* bo = (const float*)d_in[10];

  _Float16* H      = (_Float16*)d_ws;
  _Float16* X16    = H;              // 3 x 4194304 (Q,K,V fp16)
  _Float16* WT     = H + 12582912;   // 4 x 1048576 (W^T fp16)
  _Float16* qkv16  = H + 16777216;   // q,k: [B,H,S,Hd]; v: [B,H,Hd,S]
  _Float16* aout16 = H + 29360128;   // 4194304 ([B,S,D] attention out)
  float* out = (float*)d_out;

  cvt_x3<<<dim3(2048, 1, 3), 256, 0, stream>>>(Q, K, V, X16);
  cvt_w4<<<dim3(4, 256, 4), 256, 0, stream>>>(Wq, Wk, Wv, Wo, WT);
  gemm_qkv<<<dim3(32, 8, 3), 256, 0, stream>>>(X16, WT, bq, bk, bv, qkv16);
  attn_kernel<<<dim3(512), 256, 0, stream>>>(qkv16, qkv16 + 4194304,
                                             qkv16 + 8388608, aout16);
  gemm_out_k<<<dim3(32, 8), 256, 0, stream>>>(aout16, WT + 3145728, bo, out);
}